// Round 1
// baseline (603.286 us; speedup 1.0000x reference)
//
#include <hip/hip_runtime.h>
#include <cstddef>

// ---------------------------------------------------------------------------
// Problem constants: B=2, N=2048, C=1024, H=16, Dh=64, scale = Dh//H = 4
// qkv GEMM: [4096 x 1024] x [3072 x 1024]^T -> scattered into q|k|v [B,H,N,Dh]
// proj GEMM: [4096 x 1024] x [1024 x 1024]^T + bias -> d_out
// ---------------------------------------------------------------------------

#define GB_BM 128
#define GB_BN 128
#define GB_BK 16

// out[m,n] = sum_k A[m,k] * W[n,k]   (W stored row-major [Nout x K] = B^T GEMM)
// EPI=0: scatter into qkv workspace (q|k|v each [B,H,N,64])
// EPI=1: out[m*Nout + n] = acc + bias[n]
template <int EPI>
__global__ __launch_bounds__(256, 4) void gemm_bt(
    const float* __restrict__ A,
    const float* __restrict__ W,
    const float* __restrict__ bias,
    float* __restrict__ out,
    int M, int Nout, int K)
{
    __shared__ float As[GB_BK][GB_BM];   // transposed: As[k][m]
    __shared__ float Bs[GB_BK][GB_BN];   // transposed: Bs[k][n]

    const int tid = threadIdx.x;
    const int tx = tid & 15;             // 0..15  -> cols tx*4 and 64+tx*4
    const int ty = tid >> 4;             // 0..15  -> rows ty*4 and 64+ty*4
    const int m0 = blockIdx.y * GB_BM;
    const int n0 = blockIdx.x * GB_BN;

    // global staging: thread loads 8 floats of A-tile and 8 of B-tile
    const int lr = tid >> 1;             // 0..127 row in tile
    const int lc = (tid & 1) * 8;        // 0 or 8 col in tile

    const float* Ap = A + (size_t)(m0 + lr) * K + lc;
    const float* Wp = W + (size_t)(n0 + lr) * K + lc;

    float acc[8][8];
#pragma unroll
    for (int i = 0; i < 8; ++i)
#pragma unroll
        for (int j = 0; j < 8; ++j) acc[i][j] = 0.f;

    for (int k0 = 0; k0 < K; k0 += GB_BK) {
        float4 a0 = *(const float4*)(Ap + k0);
        float4 a1 = *(const float4*)(Ap + k0 + 4);
        float4 b0 = *(const float4*)(Wp + k0);
        float4 b1 = *(const float4*)(Wp + k0 + 4);
        __syncthreads();  // previous tile fully consumed before overwrite
        As[lc + 0][lr] = a0.x; As[lc + 1][lr] = a0.y; As[lc + 2][lr] = a0.z; As[lc + 3][lr] = a0.w;
        As[lc + 4][lr] = a1.x; As[lc + 5][lr] = a1.y; As[lc + 6][lr] = a1.z; As[lc + 7][lr] = a1.w;
        Bs[lc + 0][lr] = b0.x; Bs[lc + 1][lr] = b0.y; Bs[lc + 2][lr] = b0.z; Bs[lc + 3][lr] = b0.w;
        Bs[lc + 4][lr] = b1.x; Bs[lc + 5][lr] = b1.y; Bs[lc + 6][lr] = b1.z; Bs[lc + 7][lr] = b1.w;
        __syncthreads();
#pragma unroll
        for (int kk = 0; kk < GB_BK; ++kk) {
            // split fragments: addresses tx*16B -> 2-way bank alias (free)
            float4 af0 = *(const float4*)&As[kk][ty * 4];
            float4 af1 = *(const float4*)&As[kk][ty * 4 + 64];
            float4 bf0 = *(const float4*)&Bs[kk][tx * 4];
            float4 bf1 = *(const float4*)&Bs[kk][tx * 4 + 64];
            float av[8] = {af0.x, af0.y, af0.z, af0.w, af1.x, af1.y, af1.z, af1.w};
            float bv[8] = {bf0.x, bf0.y, bf0.z, bf0.w, bf1.x, bf1.y, bf1.z, bf1.w};
#pragma unroll
            for (int i = 0; i < 8; ++i)
#pragma unroll
                for (int j = 0; j < 8; ++j)
                    acc[i][j] += av[i] * bv[j];
        }
    }

#pragma unroll
    for (int i = 0; i < 8; ++i) {
        const int gm = m0 + ((i < 4) ? (ty * 4 + i) : (64 + ty * 4 + i - 4));
        if (EPI == 0) {
            const int b  = gm >> 11;       // / 2048
            const int nn = gm & 2047;
#pragma unroll
            for (int jb = 0; jb < 2; ++jb) {
                const int gn = n0 + ((jb == 0) ? (tx * 4) : (64 + tx * 4));
                const int s  = gn >> 10;          // 0:q 1:k 2:v
                const int h  = (gn >> 6) & 15;
                const int dh = gn & 63;
                float* dst = out + (size_t)s * 4194304u
                                 + (((size_t)b * 16 + h) * 2048 + nn) * 64 + dh;
                float4 v4 = make_float4(acc[i][jb * 4 + 0], acc[i][jb * 4 + 1],
                                        acc[i][jb * 4 + 2], acc[i][jb * 4 + 3]);
                *(float4*)dst = v4;
            }
        } else {
            float* rowp = out + (size_t)gm * Nout + n0;
#pragma unroll
            for (int jb = 0; jb < 2; ++jb) {
                const int c = (jb == 0) ? (tx * 4) : (64 + tx * 4);
                float4 bb = *(const float4*)(bias + n0 + c);
                float4 v4 = make_float4(acc[i][jb * 4 + 0] + bb.x,
                                        acc[i][jb * 4 + 1] + bb.y,
                                        acc[i][jb * 4 + 2] + bb.z,
                                        acc[i][jb * 4 + 3] + bb.w);
                *(float4*)(rowp + c) = v4;
            }
        }
    }
}

// S_all[bh][d] = sum_n v[bh][n][d]; grid 32*8 blocks of 64 threads, atomic combine.
__global__ void sall_sum(const float* __restrict__ vg, float* __restrict__ sall)
{
    const int bx = blockIdx.x;
    const int bh = bx >> 3;
    const int chunk = bx & 7;
    const int d = threadIdx.x;  // 0..63
    const float* base = vg + (((size_t)bh * 2048) + (size_t)chunk * 256) * 64 + d;
    float s = 0.f;
#pragma unroll 8
    for (int nn = 0; nn < 256; ++nn) s += base[(size_t)nn * 64];
    atomicAdd(&sall[bh * 64 + d], s);
}

// Banded attention with exact full-row softmax semantics (masked logits = 1e-9).
// Block = one (b,h) x 64 query rows. 256 threads: r = tid&63 (row), p = tid>>6.
__global__ __launch_bounds__(256) void attn_band(
    const float* __restrict__ qg,
    const float* __restrict__ kg,
    const float* __restrict__ vg,
    const float* __restrict__ sall,
    float* __restrict__ outp,
    const int* __restrict__ epoch_ptr)
{
    const int N = 2048;
    const int w = (epoch_ptr[0] < 15) ? 16 : 20;

    __shared__ float Kl[104][65];   // pad 65: phase-B reads spread across banks
    __shared__ float Ql[64][65];
    __shared__ float Sw[64][45];    // pad 45: phase-C row scans 2-way only
    __shared__ float PM[64];

    const int blk = blockIdx.x;
    const int bh = blk >> 5;            // 0..31 = b*16+h
    const int n0 = (blk & 31) << 6;

    const int lo = max(0, n0 - w);
    const int hi = min(N - 1, n0 + 63 + w);
    const int cnt = hi - lo + 1;        // <= 104

    const int tid = threadIdx.x;

    // Phase A: stage K rows [lo,hi] and Q rows [n0,n0+63]
    const float* kbase = kg + ((size_t)bh * N + lo) * 64;
    for (int i4 = tid; i4 < cnt * 16; i4 += 256) {
        float4 g = *(const float4*)(kbase + (size_t)i4 * 4);
        const int row = i4 >> 4, col = (i4 & 15) * 4;
        Kl[row][col] = g.x; Kl[row][col + 1] = g.y; Kl[row][col + 2] = g.z; Kl[row][col + 3] = g.w;
    }
    const float* qbase = qg + ((size_t)bh * N + n0) * 64;
    for (int i4 = tid; i4 < 64 * 16; i4 += 256) {
        float4 g = *(const float4*)(qbase + (size_t)i4 * 4);
        const int row = i4 >> 4, col = (i4 & 15) * 4;
        Ql[row][col] = g.x; Ql[row][col + 1] = g.y; Ql[row][col + 2] = g.z; Ql[row][col + 3] = g.w;
    }
    __syncthreads();

    const int r = tid & 63;
    const int p = tid >> 6;             // 0..3
    const int n = n0 + r;
    const int jlo = max(0, n - w);
    const int jhi = min(N - 1, n + w);
    const int bc = jhi - jlo + 1;       // <= 41

    // preload own q row into registers (reused across ~10 band offsets)
    float qv[64];
#pragma unroll
    for (int d = 0; d < 64; ++d) qv[d] = Ql[r][d];

    // Phase B: banded logits, scale = Dh//H = 4
    for (int off = p; off < bc; off += 4) {
        const float* krow = &Kl[jlo + off - lo][0];
        float d0 = 0.f, d1 = 0.f, d2 = 0.f, d3 = 0.f;
#pragma unroll
        for (int d = 0; d < 64; d += 4) {
            d0 += qv[d + 0] * krow[d + 0];
            d1 += qv[d + 1] * krow[d + 1];
            d2 += qv[d + 2] * krow[d + 2];
            d3 += qv[d + 3] * krow[d + 3];
        }
        Sw[r][off] = 4.0f * ((d0 + d1) + (d2 + d3));
    }
    __syncthreads();

    // Phase C: exact softmax over full row: masked entries = 1e-9, count N-bc.
    if (p == 0) {
        float m = 1e-9f;  // masked value participates in the max
        for (int off = 0; off < bc; ++off) m = fmaxf(m, Sw[r][off]);
        const float em = __expf(1e-9f - m);
        float denom = (float)(N - bc) * em;
        for (int off = 0; off < bc; ++off) {
            const float e = __expf(Sw[r][off] - m);
            Sw[r][off] = e;
            denom += e;
        }
        const float inv = 1.0f / denom;
        // fold masked-column contribution: w_j = p_j - p_mask; out += p_mask*S_all
        for (int off = 0; off < bc; ++off) Sw[r][off] = (Sw[r][off] - em) * inv;
        PM[r] = em * inv;
    }
    __syncthreads();

    // Phase D: out[n][p*16..+16] = sum_band w_j * v_j + p_mask * S_all
    float acc[16];
#pragma unroll
    for (int d = 0; d < 16; ++d) acc[d] = 0.f;

    const float* vbase = vg + ((size_t)bh * N + jlo) * 64 + p * 16;
    for (int off = 0; off < bc; ++off) {
        const float s = Sw[r][off];
        const float4* v4 = (const float4*)(vbase + (size_t)off * 64);
        float4 va = v4[0], vb = v4[1], vc = v4[2], vd = v4[3];
        acc[0]  += s * va.x; acc[1]  += s * va.y; acc[2]  += s * va.z; acc[3]  += s * va.w;
        acc[4]  += s * vb.x; acc[5]  += s * vb.y; acc[6]  += s * vb.z; acc[7]  += s * vb.w;
        acc[8]  += s * vc.x; acc[9]  += s * vc.y; acc[10] += s * vc.z; acc[11] += s * vc.w;
        acc[12] += s * vd.x; acc[13] += s * vd.y; acc[14] += s * vd.z; acc[15] += s * vd.w;
    }
    const float pm = PM[r];
    const int b = bh >> 4;
    const int h = bh & 15;
    const float* sp = sall + bh * 64 + p * 16;
    float* op = outp + (((size_t)b * N + n) * 1024) + h * 64 + p * 16;
#pragma unroll
    for (int d4 = 0; d4 < 4; ++d4) {
        float4 o;
        o.x = acc[d4 * 4 + 0] + pm * sp[d4 * 4 + 0];
        o.y = acc[d4 * 4 + 1] + pm * sp[d4 * 4 + 1];
        o.z = acc[d4 * 4 + 2] + pm * sp[d4 * 4 + 2];
        o.w = acc[d4 * 4 + 3] + pm * sp[d4 * 4 + 3];
        *(float4*)(op + d4 * 4) = o;
    }
}

extern "C" void kernel_launch(void* const* d_in, const int* in_sizes, int n_in,
                              void* d_out, int out_size, void* d_ws, size_t ws_size,
                              hipStream_t stream)
{
    const float* x      = (const float*)d_in[0];  // [2,2048,1024]
    const float* qkv_w  = (const float*)d_in[1];  // [3072,1024]
    const float* proj_w = (const float*)d_in[2];  // [1024,1024]
    const float* proj_b = (const float*)d_in[3];  // [1024]
    const int*   epoch  = (const int*)d_in[4];    // scalar
    float* out = (float*)d_out;

    float* ws = (float*)d_ws;
    const size_t BHND = (size_t)2 * 16 * 2048 * 64;  // 4,194,304 floats
    float* qw   = ws;                 // q [B,H,N,64]
    float* kw   = ws + BHND;          // k
    float* vw   = ws + 2 * BHND;      // v
    float* ao   = ws + 3 * BHND;      // attn out [B,N,1024]
    float* sall = ws + 4 * BHND;      // [32,64] column-sums of v

    hipMemsetAsync(sall, 0, 32 * 64 * sizeof(float), stream);

    gemm_bt<0><<<dim3(3072 / GB_BN, 4096 / GB_BM), dim3(256), 0, stream>>>(
        x, qkv_w, nullptr, qw, 4096, 3072, 1024);
    sall_sum<<<dim3(256), dim3(64), 0, stream>>>(vw, sall);
    attn_band<<<dim3(1024), dim3(256), 0, stream>>>(qw, kw, vw, sall, ao, epoch);
    gemm_bt<1><<<dim3(1024 / GB_BN, 4096 / GB_BM), dim3(256), 0, stream>>>(
        ao, proj_w, proj_b, out, 4096, 1024, 1024);
}

// Round 2
// 291.378 us; speedup vs baseline: 2.0705x; 2.0705x over previous
//
#include <hip/hip_runtime.h>
#include <cstddef>

// ---------------------------------------------------------------------------
// B=2, N=2048, C=1024, H=16, Dh=64, scale = Dh//H = 4
// qkv: [4096x1024] x [3072x1024]^T  -> q|k|v fp32 [B,H,N,64]   (bf16x3 split MFMA)
// attn: banded softmax (masked logits = 1e-9 folded analytically), fp32
// proj: [4096x1024] x [1024x1024]^T + bias -> out fp32          (bf16 MFMA)
// ---------------------------------------------------------------------------

typedef short  bf16x8 __attribute__((ext_vector_type(8)));
typedef float  f32x4  __attribute__((ext_vector_type(4)));

__device__ __forceinline__ void gl_lds16(const void* g, void* l) {
    __builtin_amdgcn_global_load_lds(
        (const __attribute__((address_space(1))) void*)g,
        (__attribute__((address_space(3))) void*)l, 16, 0, 0);
}

__device__ __forceinline__ ushort f2bf_rne(float f) {
    unsigned b = __float_as_uint(f);
    b += 0x7FFFu + ((b >> 16) & 1u);
    return (ushort)(b >> 16);
}

// ---------------------------------------------------------------------------
// split fp32 -> bf16 hi (+ optional lo = bf16(x - float(hi)))
// ---------------------------------------------------------------------------
template <bool WANT_LO>
__global__ void split_bf16(const float* __restrict__ src, ushort* __restrict__ hi,
                           ushort* __restrict__ lo, int n4)
{
    int i = blockIdx.x * blockDim.x + threadIdx.x;
    if (i >= n4) return;
    float4 v = ((const float4*)src)[i];
    ushort h0 = f2bf_rne(v.x), h1 = f2bf_rne(v.y), h2 = f2bf_rne(v.z), h3 = f2bf_rne(v.w);
    ((ushort4*)hi)[i] = make_ushort4(h0, h1, h2, h3);
    if constexpr (WANT_LO) {
        float r0 = v.x - __uint_as_float((unsigned)h0 << 16);
        float r1 = v.y - __uint_as_float((unsigned)h1 << 16);
        float r2 = v.z - __uint_as_float((unsigned)h2 << 16);
        float r3 = v.w - __uint_as_float((unsigned)h3 << 16);
        ((ushort4*)lo)[i] = make_ushort4(f2bf_rne(r0), f2bf_rne(r1), f2bf_rne(r2), f2bf_rne(r3));
    }
}

// ---------------------------------------------------------------------------
// MFMA GEMM, m97 structure: 128x128 tile, BK=32, 4 waves x (4x4) 16x16x32 tiles.
// A: [M x K] bf16 row-major (hi[,lo]); W: [Nout x K] bf16 row-major (hi[,lo]).
// NTERMS=3: acc += Ah*Wh + Ah*Wl + Al*Wh   (fp32-ish precision)
// EPI=0: scatter fp32 into q|k|v [B,H,N,64];  EPI=1: out = acc + bias, fp32.
// ---------------------------------------------------------------------------
template <int NTERMS, int EPI>
__global__ __launch_bounds__(256) void gemm_mfma(
    const ushort* __restrict__ Ah_g, const ushort* __restrict__ Al_g,
    const ushort* __restrict__ Wh_g, const ushort* __restrict__ Wl_g,
    const float* __restrict__ bias,
    float* __restrict__ out, int K, int Nout)
{
    __shared__ ushort smem[(NTERMS == 3 ? 4 : 2) * 4096];
    ushort* AhS = smem;
    ushort* AlS = (NTERMS == 3) ? smem + 4096 : nullptr;
    ushort* WhS = (NTERMS == 3) ? smem + 8192 : smem + 4096;
    ushort* WlS = (NTERMS == 3) ? smem + 12288 : nullptr;

    const int tid  = threadIdx.x;
    const int wid  = tid >> 6;
    const int lane = tid & 63;
    const int quad = lane >> 4;
    const int cl   = lane & 15;
    const int m0 = blockIdx.y * 128;
    const int n0 = blockIdx.x * 128;
    const int wm = (wid & 1) * 64;
    const int wn = (wid >> 1) * 64;

    const int srow = lane >> 2;        // 0..15 within a 16-row chunk
    const int scol = (lane & 3) * 8;   // bf16 col within 32

    // this wave's staging assignment
    const ushort* src; ushort* dst; int r0, c0, cn;
    if (NTERMS == 3) {
        src = (wid == 0) ? Ah_g : (wid == 1) ? Al_g : (wid == 2) ? Wh_g : Wl_g;
        dst = (wid == 0) ? AhS : (wid == 1) ? AlS : (wid == 2) ? WhS : WlS;
        r0 = (wid < 2) ? m0 : n0;
        c0 = 0; cn = 8;
    } else {
        src = (wid < 2) ? Ah_g : Wh_g;
        dst = (wid < 2) ? AhS : WhS;
        r0 = (wid < 2) ? m0 : n0;
        c0 = (wid & 1) * 4; cn = 4;
    }

    f32x4 acc[4][4];
#pragma unroll
    for (int i = 0; i < 4; ++i)
#pragma unroll
        for (int j = 0; j < 4; ++j) acc[i][j] = (f32x4){0.f, 0.f, 0.f, 0.f};

    for (int k0 = 0; k0 < K; k0 += 32) {
#pragma unroll
        for (int c = 0; c < ((NTERMS == 3) ? 8 : 4); ++c) {
            const int cc = c0 + (NTERMS == 3 ? c : (c & 3));
            if (NTERMS != 3 && c >= cn) break;
            const ushort* g = src + (size_t)(r0 + cc * 16 + srow) * K + k0 + scol;
            gl_lds16(g, dst + cc * 512);
        }
        __syncthreads();   // drains vmcnt: LDS tiles complete

        bf16x8 ah[4], wh[4];
#pragma unroll
        for (int i = 0; i < 4; ++i) {
            ah[i] = ((const bf16x8*)AhS)[(wm + i * 16 + cl) * 4 + quad];
            wh[i] = ((const bf16x8*)WhS)[(wn + i * 16 + cl) * 4 + quad];
        }
        if (NTERMS == 3) {
            bf16x8 al[4], wl[4];
#pragma unroll
            for (int i = 0; i < 4; ++i) {
                al[i] = ((const bf16x8*)AlS)[(wm + i * 16 + cl) * 4 + quad];
                wl[i] = ((const bf16x8*)WlS)[(wn + i * 16 + cl) * 4 + quad];
            }
#pragma unroll
            for (int mi = 0; mi < 4; ++mi)
#pragma unroll
                for (int ni = 0; ni < 4; ++ni) {
                    acc[mi][ni] = __builtin_amdgcn_mfma_f32_16x16x32_bf16(ah[mi], wh[ni], acc[mi][ni], 0, 0, 0);
                    acc[mi][ni] = __builtin_amdgcn_mfma_f32_16x16x32_bf16(ah[mi], wl[ni], acc[mi][ni], 0, 0, 0);
                    acc[mi][ni] = __builtin_amdgcn_mfma_f32_16x16x32_bf16(al[mi], wh[ni], acc[mi][ni], 0, 0, 0);
                }
        } else {
#pragma unroll
            for (int mi = 0; mi < 4; ++mi)
#pragma unroll
                for (int ni = 0; ni < 4; ++ni)
                    acc[mi][ni] = __builtin_amdgcn_mfma_f32_16x16x32_bf16(ah[mi], wh[ni], acc[mi][ni], 0, 0, 0);
        }
        __syncthreads();   // all waves done reading before next overwrite
    }

    // epilogue: lane (quad,cl) reg r -> m = quad*4+r, n = cl within 16x16 tile
    if (EPI == 1) {
        float bb[4];
#pragma unroll
        for (int ni = 0; ni < 4; ++ni) bb[ni] = bias[n0 + wn + ni * 16 + cl];
#pragma unroll
        for (int mi = 0; mi < 4; ++mi)
#pragma unroll
            for (int r = 0; r < 4; ++r) {
                const int gm = m0 + wm + mi * 16 + quad * 4 + r;
                float* rowp = out + (size_t)gm * Nout;
#pragma unroll
                for (int ni = 0; ni < 4; ++ni) {
                    const int gn = n0 + wn + ni * 16 + cl;
                    rowp[gn] = acc[mi][ni][r] + bb[ni];
                }
            }
    } else {
#pragma unroll
        for (int mi = 0; mi < 4; ++mi)
#pragma unroll
            for (int r = 0; r < 4; ++r) {
                const int gm = m0 + wm + mi * 16 + quad * 4 + r;
                const int b  = gm >> 11;
                const int nn = gm & 2047;
#pragma unroll
                for (int ni = 0; ni < 4; ++ni) {
                    const int gn = n0 + wn + ni * 16 + cl;
                    const int s  = gn >> 10;
                    const int h  = (gn >> 6) & 15;
                    const int dh = gn & 63;
                    out[(size_t)s * 4194304u + (((size_t)b * 16 + h) * 2048 + nn) * 64 + dh]
                        = acc[mi][ni][r];
                }
            }
    }
}

// S_all[bh][d] = sum_n v[bh][n][d]
__global__ void sall_sum(const float* __restrict__ vg, float* __restrict__ sall)
{
    const int bx = blockIdx.x;
    const int bh = bx >> 3;
    const int chunk = bx & 7;
    const int d = threadIdx.x;
    const float* base = vg + (((size_t)bh * 2048) + (size_t)chunk * 256) * 64 + d;
    float s = 0.f;
#pragma unroll 8
    for (int nn = 0; nn < 256; ++nn) s += base[(size_t)nn * 64];
    atomicAdd(&sall[bh * 64 + d], s);
}

// Banded attention, exact full-row softmax (masked logits = 1e-9), bf16 output.
__global__ __launch_bounds__(256) void attn_band(
    const float* __restrict__ qg,
    const float* __restrict__ kg,
    const float* __restrict__ vg,
    const float* __restrict__ sall,
    ushort* __restrict__ outp,
    const int* __restrict__ epoch_ptr)
{
    const int N = 2048;
    const int w = (epoch_ptr[0] < 15) ? 16 : 20;

    __shared__ float Kl[104][65];
    __shared__ float Ql[64][65];
    __shared__ float Sw[64][45];
    __shared__ float PM[64];

    const int blk = blockIdx.x;
    const int bh = blk >> 5;
    const int n0 = (blk & 31) << 6;

    const int lo = max(0, n0 - w);
    const int hi = min(N - 1, n0 + 63 + w);
    const int cnt = hi - lo + 1;

    const int tid = threadIdx.x;

    const float* kbase = kg + ((size_t)bh * N + lo) * 64;
    for (int i4 = tid; i4 < cnt * 16; i4 += 256) {
        float4 g = *(const float4*)(kbase + (size_t)i4 * 4);
        const int row = i4 >> 4, col = (i4 & 15) * 4;
        Kl[row][col] = g.x; Kl[row][col + 1] = g.y; Kl[row][col + 2] = g.z; Kl[row][col + 3] = g.w;
    }
    const float* qbase = qg + ((size_t)bh * N + n0) * 64;
    for (int i4 = tid; i4 < 64 * 16; i4 += 256) {
        float4 g = *(const float4*)(qbase + (size_t)i4 * 4);
        const int row = i4 >> 4, col = (i4 & 15) * 4;
        Ql[row][col] = g.x; Ql[row][col + 1] = g.y; Ql[row][col + 2] = g.z; Ql[row][col + 3] = g.w;
    }
    __syncthreads();

    const int r = tid & 63;
    const int p = tid >> 6;
    const int n = n0 + r;
    const int jlo = max(0, n - w);
    const int jhi = min(N - 1, n + w);
    const int bc = jhi - jlo + 1;

    float qv[64];
#pragma unroll
    for (int d = 0; d < 64; ++d) qv[d] = Ql[r][d];

    for (int off = p; off < bc; off += 4) {
        const float* krow = &Kl[jlo + off - lo][0];
        float d0 = 0.f, d1 = 0.f, d2 = 0.f, d3 = 0.f;
#pragma unroll
        for (int d = 0; d < 64; d += 4) {
            d0 += qv[d + 0] * krow[d + 0];
            d1 += qv[d + 1] * krow[d + 1];
            d2 += qv[d + 2] * krow[d + 2];
            d3 += qv[d + 3] * krow[d + 3];
        }
        Sw[r][off] = 4.0f * ((d0 + d1) + (d2 + d3));
    }
    __syncthreads();

    if (p == 0) {
        float m = 1e-9f;
        for (int off = 0; off < bc; ++off) m = fmaxf(m, Sw[r][off]);
        const float em = __expf(1e-9f - m);
        float denom = (float)(N - bc) * em;
        for (int off = 0; off < bc; ++off) {
            const float e = __expf(Sw[r][off] - m);
            Sw[r][off] = e;
            denom += e;
        }
        const float inv = 1.0f / denom;
        for (int off = 0; off < bc; ++off) Sw[r][off] = (Sw[r][off] - em) * inv;
        PM[r] = em * inv;
    }
    __syncthreads();

    float acc[16];
#pragma unroll
    for (int d = 0; d < 16; ++d) acc[d] = 0.f;

    const float* vbase = vg + ((size_t)bh * N + jlo) * 64 + p * 16;
    for (int off = 0; off < bc; ++off) {
        const float s = Sw[r][off];
        const float4* v4 = (const float4*)(vbase + (size_t)off * 64);
        float4 va = v4[0], vb = v4[1], vc = v4[2], vd = v4[3];
        acc[0]  += s * va.x; acc[1]  += s * va.y; acc[2]  += s * va.z; acc[3]  += s * va.w;
        acc[4]  += s * vb.x; acc[5]  += s * vb.y; acc[6]  += s * vb.z; acc[7]  += s * vb.w;
        acc[8]  += s * vc.x; acc[9]  += s * vc.y; acc[10] += s * vc.z; acc[11] += s * vc.w;
        acc[12] += s * vd.x; acc[13] += s * vd.y; acc[14] += s * vd.z; acc[15] += s * vd.w;
    }
    const float pm = PM[r];
    const int b = bh >> 4;
    const int h = bh & 15;
    const float* sp = sall + bh * 64 + p * 16;
    float o[16];
#pragma unroll
    for (int d = 0; d < 16; ++d) o[d] = acc[d] + pm * sp[d];

    unsigned u[8];
#pragma unroll
    for (int j = 0; j < 8; ++j)
        u[j] = (unsigned)f2bf_rne(o[2 * j]) | ((unsigned)f2bf_rne(o[2 * j + 1]) << 16);
    uint4* dstv = (uint4*)(outp + (((size_t)b * N + n) * 1024) + h * 64 + p * 16);
    dstv[0] = make_uint4(u[0], u[1], u[2], u[3]);
    dstv[1] = make_uint4(u[4], u[5], u[6], u[7]);
}

extern "C" void kernel_launch(void* const* d_in, const int* in_sizes, int n_in,
                              void* d_out, int out_size, void* d_ws, size_t ws_size,
                              hipStream_t stream)
{
    const float* x      = (const float*)d_in[0];  // [2,2048,1024]
    const float* qkv_w  = (const float*)d_in[1];  // [3072,1024]
    const float* proj_w = (const float*)d_in[2];  // [1024,1024]
    const float* proj_b = (const float*)d_in[3];  // [1024]
    const int*   epoch  = (const int*)d_in[4];
    float* out = (float*)d_out;

    const size_t BHND = (size_t)2 * 16 * 2048 * 64;   // 4,194,304
    const size_t XN = 4194304, WN = 3145728;

    float* qw   = (float*)d_ws;
    float* kw   = qw + BHND;
    float* vw   = kw + BHND;
    float* sall = vw + BHND;                  // 2048 used, pad 4096
    ushort* xh  = (ushort*)(sall + 4096);
    ushort* xl  = xh + XN;
    ushort* wh  = xl + XN;
    ushort* wl  = wh + WN;
    ushort* pwh = wl + WN;
    ushort* ao  = xh;   // alias: xh/xl dead after qkv gemm; attn writes ao later

    hipMemsetAsync(sall, 0, 2048 * sizeof(float), stream);

    split_bf16<true ><<<dim3(4096), dim3(256), 0, stream>>>(x, xh, xl, 1048576);
    split_bf16<true ><<<dim3(3072), dim3(256), 0, stream>>>(qkv_w, wh, wl, 786432);
    split_bf16<false><<<dim3(1024), dim3(256), 0, stream>>>(proj_w, pwh, nullptr, 262144);

    gemm_mfma<3, 0><<<dim3(24, 32), dim3(256), 0, stream>>>(
        xh, xl, wh, wl, nullptr, qw, 1024, 3072);

    sall_sum<<<dim3(256), dim3(64), 0, stream>>>(vw, sall);
    attn_band<<<dim3(1024), dim3(256), 0, stream>>>(qw, kw, vw, sall, ao, epoch);

    gemm_mfma<1, 1><<<dim3(8, 32), dim3(256), 0, stream>>>(
        ao, nullptr, pwh, nullptr, proj_b, out, 1024, 1024);
}

// Round 3
// 251.897 us; speedup vs baseline: 2.3950x; 1.1567x over previous
//
#include <hip/hip_runtime.h>
#include <cstddef>

// ---------------------------------------------------------------------------
// B=2, N=2048, C=1024, H=16, Dh=64, scale = Dh//H = 4
// qkv: [4096x1024] x [3072x1024]^T  -> q|k|v fp32 [B,H,N,64]   (bf16x3 split MFMA)
// attn: banded softmax (masked logits = 1e-9 folded analytically), fp32
// proj: [4096x1024] x [1024x1024]^T + bias -> out fp32          (bf16 MFMA)
// ---------------------------------------------------------------------------

typedef short  bf16x8 __attribute__((ext_vector_type(8)));
typedef float  f32x4  __attribute__((ext_vector_type(4)));

__device__ __forceinline__ void gl_lds16(const void* g, void* l) {
    __builtin_amdgcn_global_load_lds(
        (const __attribute__((address_space(1))) void*)g,
        (__attribute__((address_space(3))) void*)l, 16, 0, 0);
}

__device__ __forceinline__ ushort f2bf_rne(float f) {
    unsigned b = __float_as_uint(f);
    b += 0x7FFFu + ((b >> 16) & 1u);
    return (ushort)(b >> 16);
}

// ---------------------------------------------------------------------------
// fused fp32 -> bf16 split for all three tensors in one launch.
// x: 1048576 float4 (hi+lo), qkv_w: 786432 (hi+lo), proj_w: 262144 (hi only)
// ---------------------------------------------------------------------------
__global__ void split_all(const float* __restrict__ x,
                          const float* __restrict__ qkvw,
                          const float* __restrict__ projw,
                          ushort* __restrict__ xh, ushort* __restrict__ xl,
                          ushort* __restrict__ wh, ushort* __restrict__ wl,
                          ushort* __restrict__ pwh)
{
    const int i = blockIdx.x * 256 + threadIdx.x;
    const float* src; ushort* hi; ushort* lo; int j;
    if (i < 1048576)      { src = x;     hi = xh;  lo = xl;     j = i; }
    else if (i < 1835008) { src = qkvw;  hi = wh;  lo = wl;     j = i - 1048576; }
    else                  { src = projw; hi = pwh; lo = nullptr; j = i - 1835008; }

    float4 v = ((const float4*)src)[j];
    ushort h0 = f2bf_rne(v.x), h1 = f2bf_rne(v.y), h2 = f2bf_rne(v.z), h3 = f2bf_rne(v.w);
    ((ushort4*)hi)[j] = make_ushort4(h0, h1, h2, h3);
    if (lo) {
        float r0 = v.x - __uint_as_float((unsigned)h0 << 16);
        float r1 = v.y - __uint_as_float((unsigned)h1 << 16);
        float r2 = v.z - __uint_as_float((unsigned)h2 << 16);
        float r3 = v.w - __uint_as_float((unsigned)h3 << 16);
        ((ushort4*)lo)[j] = make_ushort4(f2bf_rne(r0), f2bf_rne(r1), f2bf_rne(r2), f2bf_rne(r3));
    }
}

// ---------------------------------------------------------------------------
// MFMA GEMM, m97 structure: 128x128 tile, BK=32, 4 waves x (4x4) 16x16x32 tiles.
// NTERMS=3: acc += Ah*Wh + Ah*Wl + Al*Wh   (fp32-ish precision)
// EPI=0: scatter fp32 into q|k|v [B,H,N,64];  EPI=1: out = acc + bias, fp32.
// ---------------------------------------------------------------------------
template <int NTERMS, int EPI>
__global__ __launch_bounds__(256) void gemm_mfma(
    const ushort* __restrict__ Ah_g, const ushort* __restrict__ Al_g,
    const ushort* __restrict__ Wh_g, const ushort* __restrict__ Wl_g,
    const float* __restrict__ bias,
    float* __restrict__ out, int K, int Nout)
{
    __shared__ ushort smem[(NTERMS == 3 ? 4 : 2) * 4096];
    ushort* AhS = smem;
    ushort* AlS = (NTERMS == 3) ? smem + 4096 : nullptr;
    ushort* WhS = (NTERMS == 3) ? smem + 8192 : smem + 4096;
    ushort* WlS = (NTERMS == 3) ? smem + 12288 : nullptr;

    const int tid  = threadIdx.x;
    const int wid  = tid >> 6;
    const int lane = tid & 63;
    const int quad = lane >> 4;
    const int cl   = lane & 15;
    const int m0 = blockIdx.y * 128;
    const int n0 = blockIdx.x * 128;
    const int wm = (wid & 1) * 64;
    const int wn = (wid >> 1) * 64;

    const int srow = lane >> 2;
    const int scol = (lane & 3) * 8;

    const ushort* src; ushort* dst; int r0, c0, cn;
    if (NTERMS == 3) {
        src = (wid == 0) ? Ah_g : (wid == 1) ? Al_g : (wid == 2) ? Wh_g : Wl_g;
        dst = (wid == 0) ? AhS : (wid == 1) ? AlS : (wid == 2) ? WhS : WlS;
        r0 = (wid < 2) ? m0 : n0;
        c0 = 0; cn = 8;
    } else {
        src = (wid < 2) ? Ah_g : Wh_g;
        dst = (wid < 2) ? AhS : WhS;
        r0 = (wid < 2) ? m0 : n0;
        c0 = (wid & 1) * 4; cn = 4;
    }

    f32x4 acc[4][4];
#pragma unroll
    for (int i = 0; i < 4; ++i)
#pragma unroll
        for (int j = 0; j < 4; ++j) acc[i][j] = (f32x4){0.f, 0.f, 0.f, 0.f};

    for (int k0 = 0; k0 < K; k0 += 32) {
#pragma unroll
        for (int c = 0; c < ((NTERMS == 3) ? 8 : 4); ++c) {
            const int cc = c0 + (NTERMS == 3 ? c : (c & 3));
            if (NTERMS != 3 && c >= cn) break;
            const ushort* g = src + (size_t)(r0 + cc * 16 + srow) * K + k0 + scol;
            gl_lds16(g, dst + cc * 512);
        }
        __syncthreads();

        bf16x8 ah[4], wh[4];
#pragma unroll
        for (int i = 0; i < 4; ++i) {
            ah[i] = ((const bf16x8*)AhS)[(wm + i * 16 + cl) * 4 + quad];
            wh[i] = ((const bf16x8*)WhS)[(wn + i * 16 + cl) * 4 + quad];
        }
        if (NTERMS == 3) {
            bf16x8 al[4], wl[4];
#pragma unroll
            for (int i = 0; i < 4; ++i) {
                al[i] = ((const bf16x8*)AlS)[(wm + i * 16 + cl) * 4 + quad];
                wl[i] = ((const bf16x8*)WlS)[(wn + i * 16 + cl) * 4 + quad];
            }
#pragma unroll
            for (int mi = 0; mi < 4; ++mi)
#pragma unroll
                for (int ni = 0; ni < 4; ++ni) {
                    acc[mi][ni] = __builtin_amdgcn_mfma_f32_16x16x32_bf16(ah[mi], wh[ni], acc[mi][ni], 0, 0, 0);
                    acc[mi][ni] = __builtin_amdgcn_mfma_f32_16x16x32_bf16(ah[mi], wl[ni], acc[mi][ni], 0, 0, 0);
                    acc[mi][ni] = __builtin_amdgcn_mfma_f32_16x16x32_bf16(al[mi], wh[ni], acc[mi][ni], 0, 0, 0);
                }
        } else {
#pragma unroll
            for (int mi = 0; mi < 4; ++mi)
#pragma unroll
                for (int ni = 0; ni < 4; ++ni)
                    acc[mi][ni] = __builtin_amdgcn_mfma_f32_16x16x32_bf16(ah[mi], wh[ni], acc[mi][ni], 0, 0, 0);
        }
        __syncthreads();
    }

    if (EPI == 1) {
        float bb[4];
#pragma unroll
        for (int ni = 0; ni < 4; ++ni) bb[ni] = bias[n0 + wn + ni * 16 + cl];
#pragma unroll
        for (int mi = 0; mi < 4; ++mi)
#pragma unroll
            for (int r = 0; r < 4; ++r) {
                const int gm = m0 + wm + mi * 16 + quad * 4 + r;
                float* rowp = out + (size_t)gm * Nout;
#pragma unroll
                for (int ni = 0; ni < 4; ++ni) {
                    const int gn = n0 + wn + ni * 16 + cl;
                    rowp[gn] = acc[mi][ni][r] + bb[ni];
                }
            }
    } else {
#pragma unroll
        for (int mi = 0; mi < 4; ++mi)
#pragma unroll
            for (int r = 0; r < 4; ++r) {
                const int gm = m0 + wm + mi * 16 + quad * 4 + r;
                const int b  = gm >> 11;
                const int nn = gm & 2047;
#pragma unroll
                for (int ni = 0; ni < 4; ++ni) {
                    const int gn = n0 + wn + ni * 16 + cl;
                    const int s  = gn >> 10;
                    const int h  = (gn >> 6) & 15;
                    const int dh = gn & 63;
                    out[(size_t)s * 4194304u + (((size_t)b * 16 + h) * 2048 + nn) * 64 + dh]
                        = acc[mi][ni][r];
                }
            }
    }
}

// S_all[bh][d] = sum_n v[bh][n][d]
__global__ void sall_sum(const float* __restrict__ vg, float* __restrict__ sall)
{
    const int bx = blockIdx.x;
    const int bh = bx >> 3;
    const int chunk = bx & 7;
    const int d = threadIdx.x;
    const float* base = vg + (((size_t)bh * 2048) + (size_t)chunk * 256) * 64 + d;
    float s = 0.f;
#pragma unroll 8
    for (int nn = 0; nn < 256; ++nn) s += base[(size_t)nn * 64];
    atomicAdd(&sall[bh * 64 + d], s);
}

// ---------------------------------------------------------------------------
// Banded attention, one barrier. Row owned by a 4-lane group inside one wave:
// rl = wid*16 + (lane>>2), p = lane&3 owns dims [p*16, p*16+16).
// Logits in registers (lg[44], fully unrolled); softmax redundant per lane.
// Only K staged in LDS: [104][68] fp32 (rows 16B-aligned, banks spread).
// ---------------------------------------------------------------------------
__global__ __launch_bounds__(256) void attn_band(
    const float* __restrict__ qg,
    const float* __restrict__ kg,
    const float* __restrict__ vg,
    const float* __restrict__ sall,
    ushort* __restrict__ outp,
    const int* __restrict__ epoch_ptr)
{
    const int N = 2048;
    const int w = (epoch_ptr[0] < 15) ? 16 : 20;

    __shared__ float Kl[104][68];   // 68: rows 16B-aligned, +4 bank rotation

    const int blk = blockIdx.x;
    const int bh  = blk >> 5;
    const int n0  = (blk & 31) << 6;
    const int lo  = max(0, n0 - w);
    const int hi  = min(N - 1, n0 + 63 + w);
    const int cnt = hi - lo + 1;        // <= 104

    const int tid  = threadIdx.x;
    const int wid  = tid >> 6;
    const int lane = tid & 63;
    const int p    = lane & 3;
    const int rl   = wid * 16 + (lane >> 2);
    const int n    = n0 + rl;

    // Q slice -> registers (coalesced: a wave covers 16 full rows)
    const float* qp = qg + ((size_t)bh * N + n) * 64 + p * 16;
    const float4 q0 = ((const float4*)qp)[0];
    const float4 q1 = ((const float4*)qp)[1];
    const float4 q2 = ((const float4*)qp)[2];
    const float4 q3 = ((const float4*)qp)[3];

    // stage K band
    const float* kbase = kg + ((size_t)bh * N + lo) * 64;
    for (int i4 = tid; i4 < cnt * 16; i4 += 256) {
        float4 g = *(const float4*)(kbase + (size_t)i4 * 4);
        const int row = i4 >> 4, col = (i4 & 15) * 4;
        *(float4*)&Kl[row][col] = g;
    }
    __syncthreads();    // the only barrier

    const int jlo = max(0, n - w);
    const int jhi = min(N - 1, n + w);
    const int bc  = jhi - jlo + 1;      // <= 41
    const int kb  = jlo - lo;

    // Phase B: logits. Each lane: 16-dim partial, 2x shfl_xor -> full dot.
    float lg[44];
#pragma unroll
    for (int o4 = 0; o4 < 11; ++o4) {
        float pa[4] = {0.f, 0.f, 0.f, 0.f};
        if (o4 * 4 < bc) {
#pragma unroll
            for (int oq = 0; oq < 4; ++oq) {
                const int off = o4 * 4 + oq;
                if (off < bc) {
                    const float* kr = &Kl[kb + off][p * 16];
                    float4 k0 = ((const float4*)kr)[0];
                    float4 k1 = ((const float4*)kr)[1];
                    float4 k2 = ((const float4*)kr)[2];
                    float4 k3 = ((const float4*)kr)[3];
                    pa[oq] = q0.x*k0.x + q0.y*k0.y + q0.z*k0.z + q0.w*k0.w
                           + q1.x*k1.x + q1.y*k1.y + q1.z*k1.z + q1.w*k1.w
                           + q2.x*k2.x + q2.y*k2.y + q2.z*k2.z + q2.w*k2.w
                           + q3.x*k3.x + q3.y*k3.y + q3.z*k3.z + q3.w*k3.w;
                }
            }
        }
#pragma unroll
        for (int oq = 0; oq < 4; ++oq) {
            float t = pa[oq];
            t += __shfl_xor(t, 1);
            t += __shfl_xor(t, 2);
            lg[o4 * 4 + oq] = 4.0f * t;
        }
    }

    // Phase C: exact full-row softmax (masked logits = 1e-9, count N-bc),
    // redundantly on all 4 lanes of the group — no communication needed.
    float m = 1e-9f;
#pragma unroll
    for (int i = 0; i < 44; ++i)
        if (i < bc) m = fmaxf(m, lg[i]);
    const float em = __expf(1e-9f - m);
    float denom = (float)(N - bc) * em;
#pragma unroll
    for (int i = 0; i < 44; ++i)
        if (i < bc) { float e = __expf(lg[i] - m); lg[i] = e; denom += e; }
    const float inv = 1.0f / denom;
    const float pm = em * inv;
#pragma unroll
    for (int i = 0; i < 44; ++i)
        if (i < bc) lg[i] = (lg[i] - em) * inv;

    // Phase D: acc over band from global V (L1-resident working set)
    float acc[16];
#pragma unroll
    for (int d = 0; d < 16; ++d) acc[d] = 0.f;
    const float* vbase = vg + ((size_t)bh * N + jlo) * 64 + p * 16;
#pragma unroll
    for (int i = 0; i < 44; ++i) {
        if (i < bc) {
            const float s = lg[i];
            const float4* v4 = (const float4*)(vbase + (size_t)i * 64);
            float4 va = v4[0], vb = v4[1], vc = v4[2], vd = v4[3];
            acc[0]  += s * va.x; acc[1]  += s * va.y; acc[2]  += s * va.z; acc[3]  += s * va.w;
            acc[4]  += s * vb.x; acc[5]  += s * vb.y; acc[6]  += s * vb.z; acc[7]  += s * vb.w;
            acc[8]  += s * vc.x; acc[9]  += s * vc.y; acc[10] += s * vc.z; acc[11] += s * vc.w;
            acc[12] += s * vd.x; acc[13] += s * vd.y; acc[14] += s * vd.z; acc[15] += s * vd.w;
        }
    }

    const int b = bh >> 4;
    const int h = bh & 15;
    const float* sp = sall + bh * 64 + p * 16;
    float4 s0 = ((const float4*)sp)[0], s1 = ((const float4*)sp)[1];
    float4 s2 = ((const float4*)sp)[2], s3 = ((const float4*)sp)[3];
    float o[16];
    o[0]  = acc[0]  + pm * s0.x; o[1]  = acc[1]  + pm * s0.y;
    o[2]  = acc[2]  + pm * s0.z; o[3]  = acc[3]  + pm * s0.w;
    o[4]  = acc[4]  + pm * s1.x; o[5]  = acc[5]  + pm * s1.y;
    o[6]  = acc[6]  + pm * s1.z; o[7]  = acc[7]  + pm * s1.w;
    o[8]  = acc[8]  + pm * s2.x; o[9]  = acc[9]  + pm * s2.y;
    o[10] = acc[10] + pm * s2.z; o[11] = acc[11] + pm * s2.w;
    o[12] = acc[12] + pm * s3.x; o[13] = acc[13] + pm * s3.y;
    o[14] = acc[14] + pm * s3.z; o[15] = acc[15] + pm * s3.w;

    unsigned u[8];
#pragma unroll
    for (int j = 0; j < 8; ++j)
        u[j] = (unsigned)f2bf_rne(o[2 * j]) | ((unsigned)f2bf_rne(o[2 * j + 1]) << 16);
    uint4* dstv = (uint4*)(outp + (((size_t)b * N + n) * 1024) + h * 64 + p * 16);
    dstv[0] = make_uint4(u[0], u[1], u[2], u[3]);
    dstv[1] = make_uint4(u[4], u[5], u[6], u[7]);
}

extern "C" void kernel_launch(void* const* d_in, const int* in_sizes, int n_in,
                              void* d_out, int out_size, void* d_ws, size_t ws_size,
                              hipStream_t stream)
{
    const float* x      = (const float*)d_in[0];
    const float* qkv_w  = (const float*)d_in[1];
    const float* proj_w = (const float*)d_in[2];
    const float* proj_b = (const float*)d_in[3];
    const int*   epoch  = (const int*)d_in[4];
    float* out = (float*)d_out;

    const size_t BHND = (size_t)2 * 16 * 2048 * 64;   // 4,194,304
    const size_t XN = 4194304, WN = 3145728;

    float* qw   = (float*)d_ws;
    float* kw   = qw + BHND;
    float* vw   = kw + BHND;
    float* sall = vw + BHND;
    ushort* xh  = (ushort*)(sall + 4096);
    ushort* xl  = xh + XN;
    ushort* wh  = xl + XN;
    ushort* wl  = wh + WN;
    ushort* pwh = wl + WN;
    ushort* ao  = xh;   // alias: xh/xl dead after qkv gemm

    hipMemsetAsync(sall, 0, 2048 * sizeof(float), stream);

    split_all<<<dim3(8192), dim3(256), 0, stream>>>(
        x, qkv_w, proj_w, xh, xl, wh, wl, pwh);

    gemm_mfma<3, 0><<<dim3(24, 32), dim3(256), 0, stream>>>(
        xh, xl, wh, wl, nullptr, qw, 1024, 3072);

    sall_sum<<<dim3(256), dim3(64), 0, stream>>>(vw, sall);
    attn_band<<<dim3(1024), dim3(256), 0, stream>>>(qw, kw, vw, sall, ao, epoch);

    gemm_mfma<1, 1><<<dim3(8, 32), dim3(256), 0, stream>>>(
        ao, nullptr, pwh, nullptr, proj_b, out, 1024, 1024);
}